// Round 1
// baseline (243.126 us; speedup 1.0000x reference)
//
#include <hip/hip_runtime.h>

typedef short short8 __attribute__((ext_vector_type(8)));
typedef float f32x4 __attribute__((ext_vector_type(4)));

#define BN_EPS 1e-5f
#define CUT_THRESH 1e-3f

__device__ __forceinline__ unsigned short f2bf(float f) {
  unsigned u = __float_as_uint(f);
  u += 0x7FFFu + ((u >> 16) & 1u);   // round-to-nearest-even
  return (unsigned short)(u >> 16);
}

// Implicit-GEMM conv 3x3 + BN + ReLU + plane-absmax.
// Block: 256 thr = 4 waves; tile = 8 rows x 32 cols x 32 Cout for one batch.
// K = 288 ordered as k = (kh*3+kw)*32 + ci  -> one MFMA K-step per tap.
__global__ __launch_bounds__(256, 2) void conv_bn_relu_kernel(
    const float* __restrict__ x, const float* __restrict__ wgt,
    const float* __restrict__ bias, const float* __restrict__ gamma,
    const float* __restrict__ beta, const float* __restrict__ rmean,
    const float* __restrict__ rvar, float* __restrict__ out,
    unsigned int* __restrict__ amax) {
  // x tile: [h:10][w:34][ci-octet g (xor-swizzled):4][ci&7:8] bf16 = 21.76 KB
  __shared__ unsigned short lx[10 * 34 * 32];
  // weights: [tap kk:9][co:32][ci:32] bf16 = 18.4 KB
  __shared__ unsigned short lw[9 * 32 * 32];

  int bid = blockIdx.x;
  // XCD-bijective swizzle: 4608 blocks = 8 XCDs * 576
  int orig = (bid & 7) * 576 + (bid >> 3);
  int b = orig / 144;
  int t = orig - b * 144;
  int tr = t / 6, tc = t - tr * 6;
  int r0 = tr * 8, c0 = tc * 32;
  int tid = threadIdx.x;

  // ---- stage x tile (fp32 global -> bf16 LDS, zero-pad borders) ----
  const float* xb = x + b * (32 * 192 * 192);
  for (int idx = tid; idx < 32 * 10 * 34; idx += 256) {
    int ci = idx / 340;
    int rem = idx - ci * 340;
    int h = rem / 34;
    int w = rem - h * 34;
    int gh = r0 - 1 + h, gw = c0 - 1 + w;
    float v = 0.f;
    if ((unsigned)gh < 192u && (unsigned)gw < 192u)
      v = xb[(ci * 192 + gh) * 192 + gw];
    lx[(h * 34 + w) * 32 + (((ci >> 3) ^ ((w >> 1) & 3)) << 3) + (ci & 7)] = f2bf(v);
  }
  // ---- stage weights ----
  for (int idx = tid; idx < 9216; idx += 256) {
    int co = idx / 288;
    int rem = idx - co * 288;
    int ci = rem / 9;
    int kk = rem - ci * 9;
    lw[(kk * 32 + co) * 32 + ci] = f2bf(wgt[idx]);
  }
  __syncthreads();

  int lane = tid & 63;
  int wv = tid >> 6;      // wave 0..3 -> rows 2wv, 2wv+1 of the 8-row tile
  int l15 = lane & 15;
  int lg = lane >> 4;

  // ---- preload all A fragments (weights) into registers: 18 x bf16x8 ----
  short8 Af[9][2];
#pragma unroll
  for (int s = 0; s < 9; ++s)
#pragma unroll
    for (int m = 0; m < 2; ++m)
      Af[s][m] = *reinterpret_cast<const short8*>(
          &lw[(s * 32 + m * 16 + l15) * 32 + lg * 8]);

  // ---- fused BN coefficients for the 8 co this thread will write ----
  float scl[2][4], sft[2][4];
#pragma unroll
  for (int m = 0; m < 2; ++m)
#pragma unroll
    for (int j = 0; j < 4; ++j) {
      int co = m * 16 + lg * 4 + j;
      float s = gamma[co] * rsqrtf(rvar[co] + BN_EPS);
      scl[m][j] = s;
      sft[m][j] = (bias[co] - rmean[co]) * s + beta[co];
    }

  f32x4 acc[2][4] = {};

  // ---- main MFMA loop: 9 taps x 4 n-tiles x 2 m-tiles ----
#pragma unroll
  for (int s = 0; s < 9; ++s) {
    const int kh = s / 3, kw = s - kh * 3;
#pragma unroll
    for (int n = 0; n < 4; ++n) {
      int hl = 2 * wv + (n >> 1) + kh;
      int wl = ((n & 1) << 4) + l15 + kw;
      short8 Bf = *reinterpret_cast<const short8*>(
          &lx[(hl * 34 + wl) * 32 + ((lg ^ ((wl >> 1) & 3)) << 3)]);
      acc[0][n] = __builtin_amdgcn_mfma_f32_16x16x32_bf16(Af[s][0], Bf, acc[0][n], 0, 0, 0);
      acc[1][n] = __builtin_amdgcn_mfma_f32_16x16x32_bf16(Af[s][1], Bf, acc[1][n], 0, 0, 0);
    }
  }

  // ---- epilogue: BN + ReLU, store, per-plane max ----
  const int HW = 192 * 192;
  float* ob = out + b * 32 * HW;
  float pmax[2][4];
#pragma unroll
  for (int m = 0; m < 2; ++m)
#pragma unroll
    for (int j = 0; j < 4; ++j) pmax[m][j] = 0.f;

#pragma unroll
  for (int m = 0; m < 2; ++m)
#pragma unroll
    for (int n = 0; n < 4; ++n) {
      int gr = r0 + 2 * wv + (n >> 1);
      int gc = c0 + ((n & 1) << 4) + l15;
#pragma unroll
      for (int j = 0; j < 4; ++j) {
        int co = m * 16 + lg * 4 + j;  // D row = (lane>>4)*4 + reg  (m89-verified)
        float v = fmaxf(acc[m][n][j] * scl[m][j] + sft[m][j], 0.f);
        ob[co * HW + gr * 192 + gc] = v;
        pmax[m][j] = fmaxf(pmax[m][j], v);
      }
    }

  // reduce max over the 16 lanes sharing each co, one atomic per group
#pragma unroll
  for (int m = 0; m < 2; ++m)
#pragma unroll
    for (int j = 0; j < 4; ++j) {
      float v = pmax[m][j];
      v = fmaxf(v, __shfl_xor(v, 1, 16));
      v = fmaxf(v, __shfl_xor(v, 2, 16));
      v = fmaxf(v, __shfl_xor(v, 4, 16));
      v = fmaxf(v, __shfl_xor(v, 8, 16));
      if (l15 == 0)
        atomicMax(&amax[b * 32 + m * 16 + lg * 4 + j], __float_as_uint(v));
    }
}

// Zero a (b,co) plane only if its absmax < CUT_THRESH (strict, matching ref).
__global__ void cut_kernel(float* __restrict__ out,
                           const unsigned int* __restrict__ amax) {
  int p = blockIdx.x;
  if (__uint_as_float(amax[p]) >= CUT_THRESH) return;  // uniform branch
  float* base = out + p * 36864;
  for (int i = threadIdx.x; i < 36864; i += 256) base[i] = 0.f;
}

extern "C" void kernel_launch(void* const* d_in, const int* in_sizes, int n_in,
                              void* d_out, int out_size, void* d_ws, size_t ws_size,
                              hipStream_t stream) {
  const float* x     = (const float*)d_in[0];
  const float* wgt   = (const float*)d_in[1];
  const float* bias  = (const float*)d_in[2];
  const float* gamma = (const float*)d_in[3];
  const float* beta  = (const float*)d_in[4];
  const float* rmean = (const float*)d_in[5];
  const float* rvar  = (const float*)d_in[6];
  float* out = (float*)d_out;
  unsigned int* amax = (unsigned int*)d_ws;

  // zero the 32*32 plane-absmax slots every call (ws is not re-poisoned)
  hipMemsetAsync(amax, 0, 1024 * sizeof(unsigned int), stream);
  conv_bn_relu_kernel<<<4608, 256, 0, stream>>>(x, wgt, bias, gamma, beta,
                                                rmean, rvar, out, amax);
  cut_kernel<<<1024, 256, 0, stream>>>(out, amax);
}

// Round 2
// 139.932 us; speedup vs baseline: 1.7375x; 1.7375x over previous
//
#include <hip/hip_runtime.h>

typedef short short8 __attribute__((ext_vector_type(8)));
typedef float f32x4 __attribute__((ext_vector_type(4)));

#define BN_EPS 1e-5f
#define CUT_THRESH 1e-3f

__device__ __forceinline__ unsigned short f2bf(float f) {
  unsigned u = __float_as_uint(f);
  u += 0x7FFFu + ((u >> 16) & 1u);  // RNE
  return (unsigned short)(u >> 16);
}

__device__ __forceinline__ void gload_lds16(const void* g, void* l) {
  __builtin_amdgcn_global_load_lds(
      (const __attribute__((address_space(1))) unsigned int*)g,
      (__attribute__((address_space(3))) unsigned int*)l, 16, 0, 0);
}

// ws layout (bytes):
//   [0, 4096)       amax  (32*32 uint, zeroed per call)
//   [4096, 22528)   wbf   (9216 bf16, [kk][co][ci] with ci-octet ^ ((co>>1)&3) swizzle)
//   [22528, 22784)  coef  (64 f32: scl[0:32], sft[32:64])
#define WS_WBF  4096
#define WS_COEF 22528

// One-time (per call) weight conversion + BN coefficient fusion.
__global__ void prep_kernel(const float* __restrict__ wgt,
                            const float* __restrict__ bias,
                            const float* __restrict__ gamma,
                            const float* __restrict__ beta,
                            const float* __restrict__ rmean,
                            const float* __restrict__ rvar,
                            unsigned short* __restrict__ wbf,
                            float* __restrict__ coef) {
  int tid = blockIdx.x * 256 + threadIdx.x;
  if (tid < 9216) {
    int co = tid / 288;         // wgt is OIHW: [co][ci][kh][kw]
    int rem = tid - co * 288;
    int ci = rem / 9;
    int kk = rem - ci * 9;
    int oct = ((ci >> 3) ^ ((co >> 1) & 3)) << 3;  // bank swizzle for A ds_read_b128
    wbf[(kk * 32 + co) * 32 + oct + (ci & 7)] = f2bf(wgt[tid]);
  }
  if (tid < 32) {
    float s = gamma[tid] * rsqrtf(rvar[tid] + BN_EPS);
    coef[tid] = s;
    coef[32 + tid] = (bias[tid] - rmean[tid]) * s + beta[tid];
  }
}

// Stage one (pixel p, ci-octet g) -> one swizzled ds_write_b128.
__device__ __forceinline__ void stage_task(int id, const float* __restrict__ xb,
                                           int r0, int c0,
                                           unsigned short* __restrict__ lx) {
  int g = id & 3;
  int p = id >> 2;              // 0..339 = h*34 + w
  int h = p / 34;
  int w = p - h * 34;
  int gh = r0 - 1 + h, gw = c0 - 1 + w;
  bool ok = ((unsigned)gh < 192u) && ((unsigned)gw < 192u);
  int ghc = min(max(gh, 0), 191);
  int gwc = min(max(gw, 0), 191);
  const float* src = xb + (g * 8) * 36864 + ghc * 192 + gwc;
  short8 v;
#pragma unroll
  for (int j = 0; j < 8; ++j) {
    float f = src[j * 36864];   // clamped addr: always safe; 8 independent loads
    f = ok ? f : 0.f;
    v[j] = (short)f2bf(f);
  }
  *reinterpret_cast<short8*>(&lx[p * 32 + ((g ^ ((w >> 1) & 3)) << 3)]) = v;
}

// Implicit-GEMM conv 3x3 + BN + ReLU + plane-absmax.
// Block: 256 thr = 4 waves; tile = 8 rows x 32 cols x 32 Cout, one batch.
__global__ __launch_bounds__(256, 3) void conv_bn_relu_kernel(
    const float* __restrict__ x,
    const unsigned short* __restrict__ wbf,
    const float* __restrict__ coef,
    float* __restrict__ out,
    unsigned int* __restrict__ amax) {
  __shared__ unsigned short lx[10 * 34 * 32];  // x tile, [p][ci-octet swz] bf16, 21.76 KB
  __shared__ unsigned short lw[9 * 32 * 32];   // weights (DMA'd linear copy of wbf), 18.4 KB

  int bid = blockIdx.x;
  // XCD-bijective swizzle: 4608 = 8 * 576
  int orig = (bid & 7) * 576 + (bid >> 3);
  int b = orig / 144;
  int t = orig - b * 144;
  int tr = t / 6, tc = t - tr * 6;
  int r0 = tr * 8, c0 = tc * 32;
  int tid = threadIdx.x;

  // ---- weights: pure DMA global->LDS, 1152 x 16B chunks (no VALU, no conflicts)
  {
    const short8* wsrc = reinterpret_cast<const short8*>(wbf);
    short8* wdst = reinterpret_cast<short8*>(lw);
#pragma unroll
    for (int r = 0; r < 4; ++r) {
      int idx = r * 256 + tid;
      gload_lds16(wsrc + idx, wdst + idx);
    }
    if (tid < 128) {
      int idx = 1024 + tid;
      gload_lds16(wsrc + idx, wdst + idx);
    }
  }

  // ---- stage x: 1360 octet-tasks, 5 unrolled rounds + tail (high MLP) ----
  const float* xb = x + b * (32 * 192 * 192);
#pragma unroll
  for (int r = 0; r < 5; ++r) stage_task(r * 256 + tid, xb, r0, c0, lx);
  if (tid < 80) stage_task(1280 + tid, xb, r0, c0, lx);

  int lane = tid & 63;
  int wv = tid >> 6;  // wave -> rows 2wv, 2wv+1 of the 8-row tile
  int l15 = lane & 15;
  int lg = lane >> 4;

  // fused BN coefficients (vector loads, overlap with barrier)
  f32x4 scl[2], sft[2];
#pragma unroll
  for (int m = 0; m < 2; ++m) {
    scl[m] = *reinterpret_cast<const f32x4*>(coef + m * 16 + lg * 4);
    sft[m] = *reinterpret_cast<const f32x4*>(coef + 32 + m * 16 + lg * 4);
  }

  __syncthreads();

  // ---- A fragments from LDS (swizzle key matches prep's) ----
  int aswz = (lg ^ ((l15 >> 1) & 3)) << 3;
  short8 Af[9][2];
#pragma unroll
  for (int s = 0; s < 9; ++s)
#pragma unroll
    for (int m = 0; m < 2; ++m)
      Af[s][m] = *reinterpret_cast<const short8*>(
          &lw[(s * 32 + m * 16 + l15) * 32 + aswz]);

  f32x4 acc[2][4] = {};

  // ---- main MFMA loop: 9 taps x 4 n-tiles x 2 m-tiles ----
#pragma unroll
  for (int s = 0; s < 9; ++s) {
    const int kh = s / 3, kw = s - kh * 3;
#pragma unroll
    for (int n = 0; n < 4; ++n) {
      int hl = 2 * wv + (n >> 1) + kh;
      int wl = ((n & 1) << 4) + l15 + kw;
      short8 Bf = *reinterpret_cast<const short8*>(
          &lx[(hl * 34 + wl) * 32 + ((lg ^ ((wl >> 1) & 3)) << 3)]);
      acc[0][n] = __builtin_amdgcn_mfma_f32_16x16x32_bf16(Af[s][0], Bf, acc[0][n], 0, 0, 0);
      acc[1][n] = __builtin_amdgcn_mfma_f32_16x16x32_bf16(Af[s][1], Bf, acc[1][n], 0, 0, 0);
    }
  }

  // ---- epilogue: BN + ReLU, store, per-plane max ----
  const int HW = 192 * 192;
  float* ob = out + b * 32 * HW;
  float pmax[2][4];
#pragma unroll
  for (int m = 0; m < 2; ++m)
#pragma unroll
    for (int j = 0; j < 4; ++j) pmax[m][j] = 0.f;

#pragma unroll
  for (int m = 0; m < 2; ++m)
#pragma unroll
    for (int n = 0; n < 4; ++n) {
      int gr = r0 + 2 * wv + (n >> 1);
      int gc = c0 + ((n & 1) << 4) + l15;
#pragma unroll
      for (int j = 0; j < 4; ++j) {
        int co = m * 16 + lg * 4 + j;  // D row = (lane>>4)*4 + reg (m89-verified)
        float v = fmaxf(acc[m][n][j] * scl[m][j] + sft[m][j], 0.f);
        ob[co * HW + gr * 192 + gc] = v;
        pmax[m][j] = fmaxf(pmax[m][j], v);
      }
    }

#pragma unroll
  for (int m = 0; m < 2; ++m)
#pragma unroll
    for (int j = 0; j < 4; ++j) {
      float v = pmax[m][j];
      v = fmaxf(v, __shfl_xor(v, 1, 16));
      v = fmaxf(v, __shfl_xor(v, 2, 16));
      v = fmaxf(v, __shfl_xor(v, 4, 16));
      v = fmaxf(v, __shfl_xor(v, 8, 16));
      if (l15 == 0)
        atomicMax(&amax[b * 32 + m * 16 + lg * 4 + j], __float_as_uint(v));
    }
}

// Zero a (b,co) plane only if its absmax < CUT_THRESH.
__global__ void cut_kernel(float* __restrict__ out,
                           const unsigned int* __restrict__ amax) {
  int p = blockIdx.x;
  if (__uint_as_float(amax[p]) >= CUT_THRESH) return;  // uniform branch
  float* base = out + p * 36864;
  for (int i = threadIdx.x; i < 36864; i += 256) base[i] = 0.f;
}

extern "C" void kernel_launch(void* const* d_in, const int* in_sizes, int n_in,
                              void* d_out, int out_size, void* d_ws, size_t ws_size,
                              hipStream_t stream) {
  const float* x     = (const float*)d_in[0];
  const float* wgt   = (const float*)d_in[1];
  const float* bias  = (const float*)d_in[2];
  const float* gamma = (const float*)d_in[3];
  const float* beta  = (const float*)d_in[4];
  const float* rmean = (const float*)d_in[5];
  const float* rvar  = (const float*)d_in[6];
  float* out = (float*)d_out;

  unsigned int*   amax = (unsigned int*)d_ws;
  unsigned short* wbf  = (unsigned short*)((char*)d_ws + WS_WBF);
  float*          coef = (float*)((char*)d_ws + WS_COEF);

  hipMemsetAsync(amax, 0, 4096, stream);
  prep_kernel<<<36, 256, 0, stream>>>(wgt, bias, gamma, beta, rmean, rvar, wbf, coef);
  conv_bn_relu_kernel<<<4608, 256, 0, stream>>>(x, wbf, coef, out, amax);
  cut_kernel<<<1024, 256, 0, stream>>>(out, amax);
}